// Round 10
// baseline (226.192 us; speedup 1.0000x reference)
//
#include <hip/hip_runtime.h>
#include <hip/hip_bf16.h>

#define DEVI __device__ __forceinline__

typedef __attribute__((ext_vector_type(8))) short short8;
typedef __attribute__((ext_vector_type(4))) short short4v;
typedef __attribute__((ext_vector_type(4))) float floatx4;

static constexpr int B_ = 2, T_ = 2048, C_ = 1024, H_ = 16, D_ = 64;
static constexpr float LOG2E = 1.44269504088896f;

DEVI float bf2f(unsigned short u) {
    union { unsigned int i; float f; } v; v.i = ((unsigned int)u) << 16; return v.f;
}
DEVI unsigned short f2bf(float f) {
    union { float f; unsigned int i; } v; v.f = f;
    unsigned int x = v.i;
    return (unsigned short)((x + 0x7fffu + ((x >> 16) & 1u)) >> 16);
}
DEVI unsigned int pk2bf(float lo, float hi) {
#if __has_builtin(__builtin_amdgcn_cvt_pk_bf16_f32)
    typedef __attribute__((ext_vector_type(2))) __bf16 bf16x2;
    union { bf16x2 v; unsigned int u; } r;
    r.v = __builtin_amdgcn_cvt_pk_bf16_f32(lo, hi);
    return r.u;
#else
    return (unsigned int)f2bf(lo) | ((unsigned int)f2bf(hi) << 16);
#endif
}
DEVI float fast_exp2(float x) {
#if __has_builtin(__builtin_amdgcn_exp2f)
    return __builtin_amdgcn_exp2f(x);
#else
    return __expf(x * 0.6931471805599453f);
#endif
}

// async global->LDS, 16B per lane. LDS dest must be wave_base + lane*16.
DEVI void async16(const unsigned short* g, unsigned short* l) {
    __builtin_amdgcn_global_load_lds((const __attribute__((address_space(1))) void*)g,
                                     (__attribute__((address_space(3))) void*)l, 16, 0, 0);
}

// ================= fused prep: x->bf16, W_attn^T (head-interleaved), W_proj^T, bias ==========
// W_attn column reorder: new row p for original col n:
//   n<1024 (q):  h=n>>6    -> p = h*128 + (n&63)
//   n<2048 (k):  h=(n-1024)>>6 -> p = h*128 + 64 + (n&63)
//   else  (v):   p = n
// so qkv-GEMM col-tile bx<16 = [q_h | k_h] for head h=bx; tiles 16..23 = v (2 heads each).
DEVI void tr_body(const float* in, unsigned short* out_base, int K, int N, int n0, int k0,
                  int tid, float (*tile)[65]) {
#pragma unroll
    for (int r = 0; r < 4; r++) {
        int ci = tid + r * 256;
        int row = ci >> 4, c4 = (ci & 15) * 4;
        float4 v = *(const float4*)&in[(size_t)(k0 + row) * N + n0 + c4];
        tile[row][c4 + 0] = v.x; tile[row][c4 + 1] = v.y;
        tile[row][c4 + 2] = v.z; tile[row][c4 + 3] = v.w;
    }
    __syncthreads();
#pragma unroll
    for (int r = 0; r < 2; r++) {
        int ci = tid + r * 256;
        int row = ci >> 3, c8 = (ci & 7) * 8;
        union { unsigned short u[8]; short8 s; } o;
#pragma unroll
        for (int j = 0; j < 8; j++) o.u[j] = f2bf(tile[c8 + j][row]);
        *(short8*)&out_base[(size_t)row * K + k0 + c8] = o.s;
    }
}

__global__ __launch_bounds__(256) void k_prep(const float* __restrict__ x,
                                              const float* __restrict__ W_attn,
                                              const float* __restrict__ W_proj,
                                              const float* __restrict__ d_bias,
                                              const float* __restrict__ w_disc,
                                              unsigned short* __restrict__ x_bf,
                                              unsigned short* __restrict__ wa_t,
                                              unsigned short* __restrict__ wp_t,
                                              float* __restrict__ bias) {
    __shared__ float tile[64][65];
    __shared__ float red[256];
    int bid = blockIdx.x, tid = threadIdx.x;
    if (bid < 2048) {
        int i = bid * 256 + tid;
        const float4* p = (const float4*)x + (size_t)i * 2;
        float4 a = p[0], b = p[1];
        union { unsigned short u[8]; short8 s; } r;
        r.u[0] = f2bf(a.x); r.u[1] = f2bf(a.y); r.u[2] = f2bf(a.z); r.u[3] = f2bf(a.w);
        r.u[4] = f2bf(b.x); r.u[5] = f2bf(b.y); r.u[6] = f2bf(b.z); r.u[7] = f2bf(b.w);
        *(short8*)&x_bf[(size_t)i * 8] = r.s;
    } else if (bid < 2816) {
        int idx = bid - 2048;
        int n0 = (idx % 48) * 64, k0 = (idx / 48) * 64;
        int p0;
        if (n0 < 1024)      p0 = (n0 >> 6) * 128;
        else if (n0 < 2048) p0 = ((n0 - 1024) >> 6) * 128 + 64;
        else                p0 = n0;
        tr_body(W_attn, wa_t + (size_t)p0 * 1024, 1024, 3072, n0, k0, tid, tile);
    } else if (bid < 3072) {
        int idx = bid - 2816;
        int n0 = (idx & 15) * 64, k0 = (idx >> 4) * 64;
        tr_body(W_proj, wp_t + (size_t)n0 * 1024, 1024, 1024, n0, k0, tid, tile);
    } else {
        int h = bid - 3072;
        float s = 0.f;
        for (int t = tid; t < T_; t += 256) s += d_bias[h * T_ + t];
        red[tid] = s;
        __syncthreads();
        for (int st = 128; st > 0; st >>= 1) {
            if (tid < st) red[tid] += red[tid + st];
            __syncthreads();
        }
        float mean = red[0] * (1.0f / T_);
        float wd = w_disc[h] * LOG2E;
        for (int t = tid; t < T_; t += 256) bias[h * T_ + t] = (d_bias[h * T_ + t] - mean) * wd;
    }
}

// ================= fused qkv GEMM: 128x128 MFMA + build/vtr epilogue =================
// LDS map (bytes): [0,8192) As | [8192,16384) Bs | epilogue reuses [0,34816) as the
// bf16 C-tile (stride 136 shorts), Wr floats at 34816, QW/KW exchange at 36864.
__global__ __launch_bounds__(256) void k_gemm_qkv(const unsigned short* __restrict__ A,
                                                  const unsigned short* __restrict__ Bt,
                                                  const float* __restrict__ W_recip,
                                                  const float* __restrict__ w_std,
                                                  const float* __restrict__ w_rec,
                                                  unsigned short* __restrict__ qe,
                                                  unsigned short* __restrict__ ke,
                                                  unsigned short* __restrict__ vt) {
    __shared__ __align__(16) char smem[45056];
    unsigned short* As = (unsigned short*)smem;
    unsigned short* Bs = (unsigned short*)(smem + 8192);
    float* Wr = (float*)(smem + 34816);
    const int K = 1024;
    int m0 = blockIdx.y * 128, bx = blockIdx.x, n0 = bx * 128;
    int tid = threadIdx.x, l = tid & 63, w = tid >> 6;
    int wm = (w >> 1) * 64, wn = (w & 1) * 64;
    int lm = l & 15, lq = l >> 4;
    for (int i = tid; i < 512; i += 256) Wr[i] = W_recip[i];   // visible after loop barriers
    floatx4 acc[4][4];
#pragma unroll
    for (int a = 0; a < 4; a++)
#pragma unroll
        for (int b = 0; b < 4; b++) acc[a][b] = {0.f, 0.f, 0.f, 0.f};

    for (int k0 = 0; k0 < K; k0 += 32) {
        __syncthreads();
#pragma unroll
        for (int r = 0; r < 2; r++) {
            int ci = tid + r * 256;
            int row = ci >> 2, off = (ci & 3) * 8;
            async16(&A[(size_t)(m0 + row) * K + k0 + off], &As[row * 32 + off]);
            async16(&Bt[(size_t)(n0 + row) * K + k0 + off], &Bs[row * 32 + off]);
        }
        __syncthreads();
        short8 af[4], bf[4];
#pragma unroll
        for (int t = 0; t < 4; t++) af[t] = *(short8*)&As[(wm + t * 16 + lm) * 32 + lq * 8];
#pragma unroll
        for (int t = 0; t < 4; t++) bf[t] = *(short8*)&Bs[(wn + t * 16 + lm) * 32 + lq * 8];
#pragma unroll
        for (int tm = 0; tm < 4; tm++)
#pragma unroll
            for (int tn = 0; tn < 4; tn++)
                acc[tm][tn] = __builtin_amdgcn_mfma_f32_16x16x32_bf16(af[tm], bf[tn], acc[tm][tn], 0, 0, 0);
    }
    __syncthreads();   // all waves done reading As/Bs before LDS reuse

    if (bx < 16) {
        // ---- q/k tile for head h=bx: build q_eff/k_eff in fragment-linear layout ----
        int h = bx;
        unsigned short* epi = (unsigned short*)smem;     // 128 x 136 shorts
#pragma unroll
        for (int tm = 0; tm < 4; tm++)
#pragma unroll
            for (int tn = 0; tn < 4; tn++)
#pragma unroll
                for (int r = 0; r < 4; r++)
                    epi[(wm + tm * 16 + lq * 4 + r) * 136 + wn + tn * 16 + lm] =
                        f2bf(acc[tm][tn][r]);
        __syncthreads();
        float* ldsw = (float*)(smem + 36864);            // 128 rows x 16 floats (QW|KW)
        int row = tid >> 1, side = tid & 1;              // side 0 = q, 1 = k
        float v64[64];
        const unsigned short* rp = epi + row * 136 + side * 64;
#pragma unroll
        for (int i = 0; i < 8; i++) {
            short8 s8 = *(const short8*)&rp[i * 8];
#pragma unroll
            for (int j = 0; j < 8; j++) v64[i * 8 + j] = bf2f((unsigned short)s8[j]);
        }
        float W8[8];
#pragma unroll
        for (int r = 0; r < 8; r++) W8[r] = 0.f;
#pragma unroll
        for (int d = 0; d < 64; d++)
#pragma unroll
            for (int r = 0; r < 8; r++) W8[r] += v64[d] * Wr[d * 8 + r];
#pragma unroll
        for (int r = 0; r < 8; r++) ldsw[row * 16 + side * 8 + r] = W8[r];
        __syncthreads();
        float ws_ = sqrtf(fmaxf(w_std[h], 1e-8f));
        float wr_ = sqrtf(fmaxf(w_rec[h], 1e-8f));
        bool ra = w_rec[h] > 0.1f;
        const float* other = &ldsw[row * 16 + (side ^ 1) * 8];  // q needs KW, k needs QW
        int m = m0 + row, b = m >> 11, t = m & 2047;
        size_t tbase = (size_t)(b * 16 + h) * 131072 + (size_t)(t >> 4) * 1024 + (size_t)(t & 15) * 8;
        float scale = side ? 1.0f : 0.125f * LOG2E;
        unsigned short* outp = side ? ke : qe;
#pragma unroll
        for (int i = 0; i < 8; i++) {
            union { unsigned short u[8]; short8 s; } o;
#pragma unroll
            for (int j = 0; j < 8; j++) {
                int d = i * 8 + j;
                float val = (ra && d >= 56) ? wr_ * other[d - 56] : ws_ * v64[d];
                o.u[j] = f2bf(val * scale);
            }
            *(short8*)&outp[tbase + (size_t)(i >> 2) * 512 + (size_t)(i & 3) * 128] = o.s;
        }
    } else {
        // ---- v tile (heads 2j, 2j+1): write vt fragment-linear straight from regs ----
        int j2 = bx - 16;
        int h = 2 * j2 + (w & 1);
#pragma unroll
        for (int tm = 0; tm < 4; tm++) {
            int t0g = m0 + wm + tm * 16 + lq * 4;
            int bb = t0g >> 11, tl = t0g & 2047;
            size_t base = (size_t)(bb * 16 + h) * 131072 + (size_t)(tl >> 5) * 2048 +
                          (size_t)((tl >> 3) & 3) * 128 + (size_t)(tl & 7);
#pragma unroll
            for (int tn = 0; tn < 4; tn++) {
                union { unsigned short u[4]; short4v s; } o;
#pragma unroll
                for (int r = 0; r < 4; r++) o.u[r] = f2bf(acc[tm][tn][r]);
                *(short4v*)&vt[base + (size_t)tn * 512 + (size_t)lm * 8] = o.s;
            }
        }
    }
}

// ================= bf16 GEMM 128x64 (fp32 out) — for the proj GEMM =================
__global__ __launch_bounds__(256) void k_gemm64(const unsigned short* __restrict__ A,
                                                const unsigned short* __restrict__ Bt,
                                                float* __restrict__ C, int M, int N, int K) {
    __shared__ __align__(16) unsigned short As[128 * 32];
    __shared__ __align__(16) unsigned short Bs[64 * 32];
    int m0 = blockIdx.y * 128, n0 = blockIdx.x * 64;
    int tid = threadIdx.x, l = tid & 63, w = tid >> 6;
    int wm = w * 32;
    int lm = l & 15, lq = l >> 4;
    floatx4 acc[2][4];
#pragma unroll
    for (int a = 0; a < 2; a++)
#pragma unroll
        for (int b = 0; b < 4; b++) acc[a][b] = {0.f, 0.f, 0.f, 0.f};

    for (int k0 = 0; k0 < K; k0 += 32) {
        __syncthreads();
#pragma unroll
        for (int r = 0; r < 2; r++) {
            int ci = tid + r * 256;
            int row = ci >> 2, off = (ci & 3) * 8;
            async16(&A[(size_t)(m0 + row) * K + k0 + off], &As[row * 32 + off]);
        }
        {
            int row = tid >> 2, off = (tid & 3) * 8;
            async16(&Bt[(size_t)(n0 + row) * K + k0 + off], &Bs[row * 32 + off]);
        }
        __syncthreads();
        short8 af[2], bf[4];
#pragma unroll
        for (int t = 0; t < 2; t++) af[t] = *(short8*)&As[(wm + t * 16 + lm) * 32 + lq * 8];
#pragma unroll
        for (int t = 0; t < 4; t++) bf[t] = *(short8*)&Bs[(t * 16 + lm) * 32 + lq * 8];
#pragma unroll
        for (int tm = 0; tm < 2; tm++)
#pragma unroll
            for (int tn = 0; tn < 4; tn++)
                acc[tm][tn] = __builtin_amdgcn_mfma_f32_16x16x32_bf16(af[tm], bf[tn], acc[tm][tn], 0, 0, 0);
    }
#pragma unroll
    for (int tm = 0; tm < 2; tm++)
#pragma unroll
        for (int tn = 0; tn < 4; tn++) {
            int row = m0 + wm + tm * 16 + lq * 4;
            int col = n0 + tn * 16 + lm;
#pragma unroll
            for (int r = 0; r < 4; r++) C[(size_t)(row + r) * N + col] = acc[tm][tn][r];
        }
}

// ================= attention helpers =================
DEVI void exp_pack(float sv[4][4], float& l_part, unsigned int pk[4][2]) {
#pragma unroll
    for (int js = 0; js < 4; js++)
#pragma unroll
        for (int r = 0; r < 4; r++) {
            float p = fast_exp2(sv[js][r]);
            sv[js][r] = p;
            l_part += p;
        }
#pragma unroll
    for (int js = 0; js < 4; js++) {
        pk[js][0] = pk2bf(sv[js][0], sv[js][1]);
        pk[js][1] = pk2bf(sv[js][2], sv[js][3]);
    }
}

DEVI short8 make_pf(const unsigned int pk[4][2], int c, int srcLo, int srcHi, bool hi) {
    int a0 = __shfl((int)pk[2 * c][0], srcLo);
    int a1 = __shfl((int)pk[2 * c][1], srcLo);
    int a2 = __shfl((int)pk[2 * c][0], srcHi);
    int a3 = __shfl((int)pk[2 * c][1], srcHi);
    int b0 = __shfl((int)pk[2 * c + 1][0], srcLo);
    int b1 = __shfl((int)pk[2 * c + 1][1], srcLo);
    int b2 = __shfl((int)pk[2 * c + 1][0], srcHi);
    int b3 = __shfl((int)pk[2 * c + 1][1], srcHi);
    union { int i[4]; short8 s; } pf;
    pf.i[0] = hi ? b0 : a0;
    pf.i[1] = hi ? b1 : a1;
    pf.i[2] = hi ? b2 : a2;
    pf.i[3] = hi ? b3 : a3;
    return pf.s;
}

struct KF { short8 lo[4]; short8 hi[4]; };
struct BV { float4 q[4]; };

// ================= flash attention: paired tiles + K&bias ping-pong + max-free softmax ======
__global__ __launch_bounds__(256) void k_attn(const unsigned short* __restrict__ qe,
                                              const unsigned short* __restrict__ ke,
                                              const unsigned short* __restrict__ vt,
                                              const float* __restrict__ bias,
                                              unsigned short* __restrict__ obf) {
    int bh = blockIdx.y;
    int b = bh >> 4, h = bh & 15;
    int tid = threadIdx.x, l = tid & 63, w = tid >> 6;
    int lm = l & 15, lq = l >> 4;
    int l8 = l * 8;
    const size_t hb = (size_t)bh * 131072;
    const unsigned short* qeh = qe + hb;
    const unsigned short* keh = ke + hb;
    const unsigned short* vth = vt + hb;
    const float* biash = bias + h * T_;

    int gA = blockIdx.x * 4 + w;            // 0..63 (light tile)
    int gB = 127 - gA;                      // 64..127 (heavy tile)
    int itA = (gA >> 2) + 1, itB = (gB >> 2) + 1;
    int irowA = gA * 16 + lm, irowB = gB * 16 + lm;

    short8 qA0 = *(const short8*)(qeh + (size_t)gA * 1024 + l8);
    short8 qA1 = *(const short8*)(qeh + (size_t)gA * 1024 + 512 + l8);
    short8 qB0 = *(const short8*)(qeh + (size_t)gB * 1024 + l8);
    short8 qB1 = *(const short8*)(qeh + (size_t)gB * 1024 + 512 + l8);

    floatx4 OA[4], OB[4];
#pragma unroll
    for (int i = 0; i < 4; i++) { OA[i] = {0.f, 0.f, 0.f, 0.f}; OB[i] = {0.f, 0.f, 0.f, 0.f}; }
    float lA = 0.f, lB = 0.f;               // per-lane partial denominators

    const int srcLo = ((lq & 1) * 2) * 16 + lm;
    const int srcHi = srcLo + 16;
    const bool hi = (lq >> 1) & 1;

    KF kfa, kfb;
    BV bva, bvb;
#pragma unroll
    for (int js = 0; js < 4; js++) {
        const unsigned short* kp = keh + (size_t)js * 1024 + l8;
        kfa.lo[js] = *(const short8*)kp;
        kfa.hi[js] = *(const short8*)(kp + 512);
        bva.q[js] = *(const float4*)&biash[js * 16 + lq * 4];
    }

    auto step = [&](int s, KF& cur, KF& nxt, BV& bcur, BV& bnxt) {
        int j0 = s * 64;
        bool doA = (s < itA);
        bool maskA = (s == itA - 1);
        bool maskB = (s == itB - 1);
        int sp = (s + 1 < itB) ? s + 1 : s;   // clamp bias prefetch (stay in buffer)
        // prefetch next K tile (overread past last tile lands in vt: harmless) + next bias
        {
            const unsigned short* kb = keh + (size_t)(s + 1) * 4096 + l8;
#pragma unroll
            for (int js = 0; js < 4; js++) {
                nxt.lo[js] = *(const short8*)(kb + js * 1024);
                nxt.hi[js] = *(const short8*)(kb + js * 1024 + 512);
                bnxt.q[js] = *(const float4*)&biash[sp * 64 + js * 16 + lq * 4];
            }
        }
        // V fragments for this tile (issued early to overlap the VALU chain)
        short8 vfr[2][4];
#pragma unroll
        for (int c = 0; c < 2; c++)
#pragma unroll
            for (int dt = 0; dt < 4; dt++)
                vfr[c][dt] = *(const short8*)(vth + (size_t)((j0 >> 5) + c) * 2048 + dt * 512 + l8);
        // QK MFMAs, zero C-init (B always, A if live)
        floatx4 sb4[4], sa4[4];
#pragma unroll
        for (int js = 0; js < 4; js++) {
            floatx4 sb = {0.f, 0.f, 0.f, 0.f};
            sb = __builtin_amdgcn_mfma_f32_16x16x32_bf16(cur.lo[js], qB0, sb, 0, 0, 0);
            sb = __builtin_amdgcn_mfma_f32_16x16x32_bf16(cur.hi[js], qB1, sb, 0, 0, 0);
            sb4[js] = sb;
        }
        if (doA) {
#pragma unroll
            for (int js = 0; js < 4; js++) {
                floatx4 sa = {0.f, 0.f, 0.f, 0.f};
                sa = __builtin_amdgcn_mfma_f32_16x16x32_bf16(cur.lo[js], qA0, sa, 0, 0, 0);
                sa = __builtin_amdgcn_mfma_f32_16x16x32_bf16(cur.hi[js], qA1, sa, 0, 0, 0);
                sa4[js] = sa;
            }
        }
        // stream B: add (pre-fetched) bias, mask diagonal, exp
        float svB[4][4];
#pragma unroll
        for (int js = 0; js < 4; js++) {
            svB[js][0] = sb4[js][0] + bcur.q[js].x;
            svB[js][1] = sb4[js][1] + bcur.q[js].y;
            svB[js][2] = sb4[js][2] + bcur.q[js].z;
            svB[js][3] = sb4[js][3] + bcur.q[js].w;
        }
        if (maskB) {
#pragma unroll
            for (int js = 0; js < 4; js++) {
                int jb = j0 + js * 16 + lq * 4;
#pragma unroll
                for (int r = 0; r < 4; r++)
                    if (jb + r > irowB) svB[js][r] = -1e9f;   // exp2 -> 0
            }
        }
        unsigned int pkB[4][2];
        exp_pack(svB, lB, pkB);

        if (doA) {
            float svA[4][4];
#pragma unroll
            for (int js = 0; js < 4; js++) {
                svA[js][0] = sa4[js][0] + bcur.q[js].x;
                svA[js][1] = sa4[js][1] + bcur.q[js].y;
                svA[js][2] = sa4[js][2] + bcur.q[js].z;
                svA[js][3] = sa4[js][3] + bcur.q[js].w;
            }
            if (maskA) {
#pragma unroll
                for (int js = 0; js < 4; js++) {
                    int jb = j0 + js * 16 + lq * 4;
#pragma unroll
                    for (int r = 0; r < 4; r++)
                        if (jb + r > irowA) svA[js][r] = -1e9f;
                }
            }
            unsigned int pkA[4][2];
            exp_pack(svA, lA, pkA);
#pragma unroll
            for (int c = 0; c < 2; c++) {
                short8 pfA = make_pf(pkA, c, srcLo, srcHi, hi);
                short8 pfB = make_pf(pkB, c, srcLo, srcHi, hi);
#pragma unroll
                for (int dt = 0; dt < 4; dt++) {
                    OA[dt] = __builtin_amdgcn_mfma_f32_16x16x32_bf16(vfr[c][dt], pfA, OA[dt], 0, 0, 0);
                    OB[dt] = __builtin_amdgcn_mfma_f32_16x16x32_bf16(vfr[c][dt], pfB, OB[dt], 0, 0, 0);
                }
            }
        } else {
#pragma unroll
            for (int c = 0; c < 2; c++) {
                short8 pfB = make_pf(pkB, c, srcLo, srcHi, hi);
#pragma unroll
                for (int dt = 0; dt < 4; dt++)
                    OB[dt] = __builtin_amdgcn_mfma_f32_16x16x32_bf16(vfr[c][dt], pfB, OB[dt], 0, 0, 0);
            }
        }
    };

    int s = 0;
    for (; s + 2 <= itB; s += 2) {       // ping-pong: no register-swap movs
        step(s, kfa, kfb, bva, bvb);
        step(s + 1, kfb, kfa, bvb, bva);
    }
    if (s < itB) step(s, kfa, kfb, bva, bvb);

    // epilogue: reduce the per-lane partial denominators across quads, then write
    lA += __shfl_xor(lA, 16); lA += __shfl_xor(lA, 32);
    lB += __shfl_xor(lB, 16); lB += __shfl_xor(lB, 32);
    {
        float inv = 1.0f / lA;
        unsigned short* orow = obf + (size_t)(b * T_ + irowA) * C_ + h * 64;
#pragma unroll
        for (int dt = 0; dt < 4; dt++) {
            union { unsigned short u[4]; short4v s4; } o;
#pragma unroll
            for (int r = 0; r < 4; r++) o.u[r] = f2bf(OA[dt][r] * inv);
            *(short4v*)&orow[dt * 16 + lq * 4] = o.s4;
        }
    }
    {
        float inv = 1.0f / lB;
        unsigned short* orow = obf + (size_t)(b * T_ + irowB) * C_ + h * 64;
#pragma unroll
        for (int dt = 0; dt < 4; dt++) {
            union { unsigned short u[4]; short4v s4; } o;
#pragma unroll
            for (int r = 0; r < 4; r++) o.u[r] = f2bf(OB[dt][r] * inv);
            *(short4v*)&orow[dt * 16 + lq * 4] = o.s4;
        }
    }
}

extern "C" void kernel_launch(void* const* d_in, const int* in_sizes, int n_in,
                              void* d_out, int out_size, void* d_ws, size_t ws_size,
                              hipStream_t stream) {
    const float* x       = (const float*)d_in[0];
    const float* W_attn  = (const float*)d_in[1];
    const float* W_proj  = (const float*)d_in[2];
    const float* W_recip = (const float*)d_in[3];
    const float* w_std   = (const float*)d_in[4];
    const float* w_rec   = (const float*)d_in[5];
    const float* w_disc  = (const float*)d_in[6];
    const float* d_bias  = (const float*)d_in[7];

    char* ws = (char*)d_ws;
    size_t o = 0;
    unsigned short* x_bf = (unsigned short*)(ws + o); o += (size_t)4096 * 1024 * 2;
    unsigned short* wa_t = (unsigned short*)(ws + o); o += (size_t)3072 * 1024 * 2;
    unsigned short* wp_t = (unsigned short*)(ws + o); o += (size_t)1024 * 1024 * 2;
    unsigned short* qe   = (unsigned short*)(ws + o); o += (size_t)32 * 2048 * 64 * 2;
    unsigned short* ke   = (unsigned short*)(ws + o); o += (size_t)32 * 2048 * 64 * 2;  // k_attn overreads ~8KB into vt: harmless
    unsigned short* vt   = (unsigned short*)(ws + o); o += (size_t)32 * 2048 * 64 * 2;
    unsigned short* obf  = (unsigned short*)(ws + o); o += (size_t)4096 * 1024 * 2;
    float* bias          = (float*)(ws + o);          o += (size_t)16 * 2048 * 4;

    k_prep<<<3088, 256, 0, stream>>>(x, W_attn, W_proj, d_bias, w_disc, x_bf, wa_t, wp_t, bias);
    k_gemm_qkv<<<dim3(24, 32), 256, 0, stream>>>(x_bf, wa_t, W_recip, w_std, w_rec, qe, ke, vt);
    k_attn<<<dim3(16, 32), 256, 0, stream>>>(qe, ke, vt, bias, obf);
    k_gemm64<<<dim3(16, 32), 256, 0, stream>>>(obf, wp_t, (float*)d_out, 4096, 1024, 1024);
}